// Round 14
// baseline (112.883 us; speedup 1.0000x reference)
//
#include <hip/hip_runtime.h>
#include <hip/hip_bf16.h>

constexpr int Bn = 8, Hn = 512, Ln = 4096, N2n = 32;

typedef _Float16 f16;
typedef __attribute__((ext_vector_type(8))) _Float16 f16x8;
typedef __attribute__((ext_vector_type(4))) _Float16 f16x4;
typedef __attribute__((ext_vector_type(2))) _Float16 f16x2;
typedef __attribute__((ext_vector_type(4))) float f32x4;

typedef void __attribute__((address_space(1))) gvoid;
typedef void __attribute__((address_space(3))) lvoid;

// ============ K0: per-h param matrices (V, full A3 incl Toeplitz, w64) ============
__global__ __launch_bounds__(64) void k_mats1(
    const float* __restrict__ C, const float* __restrict__ log_dt,
    const float* __restrict__ logA, const float* __restrict__ Aim,
    f16* __restrict__ Vg, f16* __restrict__ A3g, float2* __restrict__ w64g) {
  __shared__ f16 VT[64 * 64];
  __shared__ f16 QT[64 * 64];
  __shared__ float kp[64][33];
  __shared__ float ks[64];
  const int h = blockIdx.x, tid = threadIdx.x, n = tid & 31;

  if (tid < 32) {
    const int idx = h * N2n + n;
    float dt = expf(log_dt[h]);
    float Ar = -expf(logA[idx]);
    float Ai = Aim[idx];
    float dr = Ar * dt, di = Ai * dt;
    float er = expf(dr);
    float wr = er * cosf(di), wi = er * sinf(di);
    float den = Ar * Ar + Ai * Ai;
    float e1r = wr - 1.0f, e1i = wi;
    float tr = (e1r * Ar + e1i * Ai) / den;
    float ti = (e1i * Ar - e1r * Ai) / den;
    float Cr = C[idx * 2 + 0], Ci = C[idx * 2 + 1];
    float c2r = 2.0f * (Cr * tr - Ci * ti);
    float c2i = 2.0f * (Cr * ti + Ci * tr);

    float wpr = 1.f, wpi = 0.f;   // w^p
    for (int p = 0; p <= 64; ++p) {
      float cwr = c2r * wpr - c2i * wpi;   // C2 * w^p
      float cwi = c2r * wpi + c2i * wpr;
      if (p < 64) {
        const int j = 63 - p, ch = j >> 3, jo = j & 7;
        const int s0 = 2 * n, s1 = 2 * n + 1;
        VT[s0 * 64 + ((ch ^ (s0 & 7)) * 8) + jo] = (f16)wpr;
        VT[s1 * 64 + ((ch ^ (s1 & 7)) * 8) + jo] = (f16)wpi;
        kp[p][n] = cwr;
      }
      if (p >= 1) {
        const int t = p - 1, c0 = 2 * n;
        const int ch = (c0 >> 3) ^ (t & 7);
        QT[t * 64 + ch * 8 + (c0 & 7)]     = (f16)cwr;
        QT[t * 64 + ch * 8 + (c0 & 7) + 1] = (f16)(-cwi);
      }
      if (p == 64) w64g[h * 32 + n] = make_float2(wpr, wpi);
      float nr = wpr * wr - wpi * wi;
      float ni = wpr * wi + wpi * wr;
      wpr = nr; wpi = ni;
    }
  }
  __syncthreads();
  float s = 0.f;
#pragma unroll
  for (int m = 0; m < 32; ++m) s += kp[tid][m];
  ks[tid] = s;
  __syncthreads();
  const int t = tid;
#pragma unroll
  for (int c = 0; c < 8; ++c) {
    f16x8 row;
#pragma unroll
    for (int jo = 0; jo < 8; ++jo) {
      int j = c * 8 + jo;
      row[jo] = (j <= t) ? (f16)ks[t - j] : (f16)0.f;
    }
    *(f16x8*)&A3g[(size_t)h * 8192 + t * 128 + ((c ^ (t & 7)) * 8)] = row;
  }
#pragma unroll
  for (int c = 0; c < 8; ++c)
    *(f16x8*)&Vg[(size_t)h * 4096 + tid * 64 + c * 8] = *(f16x8*)&VT[tid * 64 + c * 8];
#pragma unroll
  for (int c = 0; c < 8; ++c)
    *(f16x8*)&A3g[(size_t)h * 8192 + tid * 128 + 64 + c * 8] = *(f16x8*)&QT[tid * 64 + c * 8];
}

// ============ K1: W fp32 -> f16 (row-major) ============
__global__ void conv_w(const float* __restrict__ W, f16* __restrict__ Wh) {
  int i = blockIdx.x * 256 + threadIdx.x;
  if (i < 2 * Hn * Hn) Wh[i] = (f16)W[i];
}

// ============ K2: fused middle, one block per (h,b): ~33 KB LDS ============
__global__ __launch_bounds__(256, 4) void s4d_mid(
    const float* __restrict__ u, const f16* __restrict__ Vg,
    const f16* __restrict__ A3g, const float2* __restrict__ w64g,
    const float* __restrict__ Dv, f16* __restrict__ yg) {
  __shared__ f16 MATS[8192];   // 16 KB: V in [0:4096), then A3 overwrites
  __shared__ f16 U[4096];      // 8 KB: [col=blk][j] chunk^(col&7)
  __shared__ f16 LE[4096];     // 8 KB: [col=blk][st] chunk^(col&7)
  __shared__ float2 Pbuf[4][32];  // 1 KB: quarter end-states
  const int tid = threadIdx.x, wid = tid >> 6, lane = tid & 63;
  const int h = ((blockIdx.x >> 6) << 3) | (blockIdx.x & 7);
  const int b = (blockIdx.x >> 3) & 7;
  const float Dh = Dv[h];

#pragma unroll
  for (int q = 0; q < 2; ++q)
    __builtin_amdgcn_global_load_lds((const gvoid*)(Vg + (size_t)h * 4096 + (q * 256 + tid) * 8),
                                     (lvoid*)&MATS[(q * 256 + wid * 64) * 8], 16, 0, 0);
#pragma unroll
  for (int i = 0; i < 4; ++i) {
    int e = (i * 256 + tid) * 4;          // 0..4095
    float4 uv = *(const float4*)(u + ((size_t)(b * Hn + h)) * Ln + e);
    int col = e >> 6, j = e & 63;
    f16x4 hv = {(f16)uv.x, (f16)uv.y, (f16)uv.z, (f16)uv.w};
    *(f16x4*)&U[col * 64 + ((j >> 3) ^ (col & 7)) * 8 + (j & 7)] = hv;
  }
  asm volatile("s_waitcnt vmcnt(0)" ::: "memory");
  __syncthreads();

  // ---- MFMA1: L = V · u  (M=64 st, N=64 cols, K=64) ----
  const int col = wid * 16 + (lane & 15);
  f32x4 acc[4];
#pragma unroll
  for (int i = 0; i < 4; ++i) acc[i] = (f32x4){0.f, 0.f, 0.f, 0.f};
#pragma unroll
  for (int ks = 0; ks < 2; ++ks) {
    const int kc = ks * 4 + (lane >> 4);
    f16x8 bv = *(const f16x8*)&U[col * 64 + ((kc ^ (col & 7)) * 8)];
#pragma unroll
    for (int mf = 0; mf < 4; ++mf) {
      int row = mf * 16 + (lane & 15);
      f16x8 a = *(const f16x8*)&MATS[row * 64 + ((kc ^ (row & 7)) * 8)];
      acc[mf] = __builtin_amdgcn_mfma_f32_16x16x32_f16(a, bv, acc[mf], 0, 0, 0);
    }
  }
  __syncthreads();   // V reads drained; safe to overwrite MATS

#pragma unroll
  for (int q = 0; q < 4; ++q)
    __builtin_amdgcn_global_load_lds((const gvoid*)(A3g + (size_t)h * 8192 + (q * 256 + tid) * 8),
                                     (lvoid*)&MATS[(q * 256 + wid * 64) * 8], 16, 0, 0);

#pragma unroll
  for (int mf = 0; mf < 4; ++mf) {
    int st0 = mf * 16 + (lane >> 4) * 4;
    f16x4 o = {(f16)acc[mf][0], (f16)acc[mf][1], (f16)acc[mf][2], (f16)acc[mf][3]};
    *(f16x4*)&LE[col * 64 + (((st0 >> 3) ^ (col & 7)) << 3) + (st0 & 7)] = o;
  }
  __syncthreads();

  // ---- parallel in-LDS scan: wave q handles blocks 16q..16q+15 (lanes 0..31) ----
  {
    const int n = lane & 31, q = wid;
    const float2 wT = w64g[h * 32 + n];
    float qr = wT.x, qi = wT.y;
#pragma unroll
    for (int s = 0; s < 4; ++s) {
      float nr = qr * qr - qi * qi;
      float ni = 2.f * qr * qi;
      qr = nr; qi = ni;
    }
    f16x2 Lb[16];
    float er = 0.f, ei = 0.f;
    if (lane < 32) {
#pragma unroll
      for (int k = 0; k < 16; ++k) {
        int blk = q * 16 + k;
        int fi = blk * 64 + (((n >> 2) ^ (blk & 7)) << 3) + ((n & 3) << 1);
        Lb[k] = *(const f16x2*)&LE[fi];
      }
#pragma unroll
      for (int k = 0; k < 16; ++k) {
        float nr = fmaf(wT.x, er, fmaf(-wT.y, ei, (float)Lb[k][0]));
        float ni = fmaf(wT.y, er, fmaf(wT.x, ei, (float)Lb[k][1]));
        er = nr; ei = ni;
      }
      Pbuf[q][n] = make_float2(er, ei);
    }
    __syncthreads();
    if (lane < 32) {
      float orr = 0.f, oii = 0.f;
      for (int p = 0; p < q; ++p) {
        float2 Pp = Pbuf[p][n];
        float nr = fmaf(qr, orr, fmaf(-qi, oii, Pp.x));
        float ni = fmaf(qi, orr, fmaf(qr, oii, Pp.y));
        orr = nr; oii = ni;
      }
      er = orr; ei = oii;
#pragma unroll
      for (int k = 0; k < 16; ++k) {
        int blk = q * 16 + k;
        int fi = blk * 64 + (((n >> 2) ^ (blk & 7)) << 3) + ((n & 3) << 1);
        *(f16x2*)&LE[fi] = (f16x2){(f16)er, (f16)ei};
        float nr = fmaf(wT.x, er, fmaf(-wT.y, ei, (float)Lb[k][0]));
        float ni = fmaf(wT.y, er, fmaf(wT.x, ei, (float)Lb[k][1]));
        er = nr; ei = ni;
      }
    }
  }
  asm volatile("s_waitcnt vmcnt(0)" ::: "memory");
  __syncthreads();

  // ---- y-GEMM: A = A3 (MATS 64x128), B = [U | LE] read in place ----
  f32x4 acc4[4];
#pragma unroll
  for (int i = 0; i < 4; ++i) acc4[i] = (f32x4){0.f, 0.f, 0.f, 0.f};
#pragma unroll
  for (int ks = 0; ks < 4; ++ks) {
    const int kc = ks * 4 + (lane >> 4);
    f16x8 bf;
    if (ks < 2) bf = *(const f16x8*)&U[col * 64 + ((kc ^ (col & 7)) << 3)];
    else        bf = *(const f16x8*)&LE[col * 64 + (((kc - 8) ^ (col & 7)) << 3)];
#pragma unroll
    for (int mf = 0; mf < 4; ++mf) {
      int row = mf * 16 + (lane & 15);
      f16x8 af = *(const f16x8*)&MATS[row * 128 + ((kc ^ (row & 7)) << 3)];
      acc4[mf] = __builtin_amdgcn_mfma_f32_16x16x32_f16(af, bf, acc4[mf], 0, 0, 0);
    }
  }
  const int t0 = (lane >> 4) * 4;
#pragma unroll
  for (int mf = 0; mf < 4; ++mf) {
    const int tb = mf * 16 + t0;
    f16x4 uq = *(const f16x4*)&U[col * 64 + (((tb >> 3) ^ (col & 7)) << 3) + (tb & 7)];
    f16x4 o;
#pragma unroll
    for (int r = 0; r < 4; ++r) {
      float v = acc4[mf][r] + Dh * (float)uq[r];
      float g2 = v * fmaf(0.0713548163f, v * v, 1.5957691216f);
      o[r] = (f16)(v * __builtin_amdgcn_rcpf(1.0f + __expf(-g2)));
    }
    *(f16x4*)&yg[((size_t)(b * Hn + h)) * Ln + col * 64 + tb] = o;
  }
}

// ============ K5: transpose y[b][h][l] -> gyT[b][l][h] ============
__global__ __launch_bounds__(256) void k_transpose(
    const f16* __restrict__ yg, f16* __restrict__ gyT) {
  __shared__ float T[64][65];
  const int bid = blockIdx.x, tid = threadIdx.x;
  const int b = bid >> 9, hg = (bid >> 6) & 7, lg = bid & 63;
  const int h0 = hg * 64, l0 = lg * 64;
  const int hi = tid >> 2, lc = (tid & 3) * 16;
  const f16* src = yg + ((size_t)(b * Hn + h0 + hi)) * Ln + l0 + lc;
  f16x8 v0 = *(const f16x8*)src;
  f16x8 v1 = *(const f16x8*)(src + 8);
#pragma unroll
  for (int e = 0; e < 8; ++e) T[lc + e][hi] = (float)v0[e];
#pragma unroll
  for (int e = 0; e < 8; ++e) T[lc + 8 + e][hi] = (float)v1[e];
  __syncthreads();
  const int li = tid >> 2, hc = (tid & 3) * 16;
  f16x8 o0, o1;
#pragma unroll
  for (int e = 0; e < 8; ++e) o0[e] = (f16)T[li][hc + e];
#pragma unroll
  for (int e = 0; e < 8; ++e) o1[e] = (f16)T[li][hc + 8 + e];
  f16* dst = gyT + ((size_t)b * Ln + l0 + li) * Hn + h0 + hc;
  *(f16x8*)dst = o0;
  *(f16x8*)(dst + 8) = o1;
}

// ============ K6: dual GEMM (a,g) + bias + GLU — 64-dual x 128, BK=64, counted-vmcnt dbuf ============
// 4 waves (isG x wn). Double-buffered 64 KB LDS, 2 blocks/CU. Schedule: stage t+2 after
// compute barrier; vmcnt(8) at tile top keeps next tile's 8 loads/thread in flight
// (T4: never drain to 0 in the loop). Proven 8-chunk row-XOR swizzle (128B rows).
__global__ __launch_bounds__(256, 2) void s4d_gemm(
    const f16* __restrict__ Wh, const f16* __restrict__ gyT,
    const float* __restrict__ bias, float* __restrict__ out) {
  __shared__ f16 As[2][2][64][64];   // [buf][role][h-row][k] 32 KB
  __shared__ f16 Bs[2][128][64];     // [buf][l-row][k]       32 KB
  __shared__ float biasS[2][64];
  const int tid = threadIdx.x;
  const int wid = tid >> 6, lane = tid & 63;
  const int nt = blockIdx.x & 255;        // b (8) x l-tile (32 of 128)
  const int mt = blockIdx.x >> 8;         // 8 M-tiles of 64-dual
  const int b = nt >> 5;
  const int l0 = (nt & 31) * 128;
  const int m0 = mt * 64;
  const int isG = wid >> 1;               // 0: a-waves, 1: g-waves
  const int wn = wid & 1;                 // l-half

  if (tid < 64) biasS[0][tid] = bias[m0 + tid];
  else if (tid < 128) biasS[1][tid - 64] = bias[Hn + m0 + (tid - 64)];

  const int srow = lane >> 3;              // row within 8-row group
  const int sks = ((lane & 7) ^ srow) * 8; // inverse-swizzled source k-offset

  // 8 loads/thread per tile: 4 A-groups (2 roles x 64 rows) + 4 B-groups (128 rows)
#define STAGE(BUF, KT)                                                                    \
  {                                                                                       \
    const int k0 = (KT) * 64;                                                             \
    _Pragma("unroll")                                                                     \
    for (int q = 0; q < 4; ++q) {                                                         \
      const int ga = q * 4 + wid;          /* 0..15 */                                    \
      const int role = ga >> 3, r0a = (ga & 7) * 8;                                       \
      const f16* srcA = Wh + ((size_t)(role * Hn + m0 + r0a + srow) * 512 + k0 + sks);    \
      __builtin_amdgcn_global_load_lds((const gvoid*)srcA,                                \
          (lvoid*)&As[BUF][role][r0a][0], 16, 0, 0);                                      \
      const int rb = ga * 8;               /* 0..120 */                                   \
      const f16* srcB = gyT + (((size_t)b * Ln + l0 + rb + srow) * Hn + k0 + sks);        \
      __builtin_amdgcn_global_load_lds((const gvoid*)srcB,                                \
          (lvoid*)&Bs[BUF][rb][0], 16, 0, 0);                                             \
    }                                                                                     \
  }

  f32x4 acc[4][4];
#pragma unroll
  for (int i = 0; i < 4; ++i)
#pragma unroll
    for (int j = 0; j < 4; ++j) acc[i][j] = (f32x4){0.f, 0.f, 0.f, 0.f};

  STAGE(0, 0);
  STAGE(1, 1);

#pragma unroll
  for (int t = 0; t < 8; ++t) {
    const int cur = t & 1;
    if (t < 7) { asm volatile("s_waitcnt vmcnt(8)" ::: "memory"); }
    else       { asm volatile("s_waitcnt vmcnt(0)" ::: "memory"); }
    __builtin_amdgcn_s_barrier();          // all waves' tile-t loads landed
    __builtin_amdgcn_sched_barrier(0);
#pragma unroll
    for (int kk = 0; kk < 2; ++kk) {
      const int kc = kk * 4 + (lane >> 4);
      f16x8 af[4], bf[4];
#pragma unroll
      for (int mf = 0; mf < 4; ++mf) {
        const int row = mf * 16 + (lane & 15);
        af[mf] = *(const f16x8*)&As[cur][isG][row][(kc ^ (row & 7)) * 8];
      }
#pragma unroll
      for (int nf = 0; nf < 4; ++nf) {
        const int cl = wn * 64 + nf * 16 + (lane & 15);
        bf[nf] = *(const f16x8*)&Bs[cur][cl][(kc ^ (cl & 7)) * 8];
      }
#pragma unroll
      for (int mf = 0; mf < 4; ++mf)
#pragma unroll
        for (int nf = 0; nf < 4; ++nf)
          acc[mf][nf] = __builtin_amdgcn_mfma_f32_16x16x32_f16(af[mf], bf[nf], acc[mf][nf], 0, 0, 0);
    }
    __builtin_amdgcn_sched_barrier(0);
    __builtin_amdgcn_s_barrier();          // all waves done reading buf[cur]
    if (t < 6) STAGE(cur, t + 2);          // refill the buffer just freed
  }

  // ---- epilogue: g-waves -> sigmoid f16 into SIG (reuses Bs[0], all reads done) ----
  __syncthreads();
  f16 (*SIG)[64][64] = (f16(*)[64][64]) & Bs[0][0][0];   // [wn][h-row][l-col] 16 KB
  const int r0e = (lane >> 4) * 4, c0 = lane & 15;
  if (isG) {
#pragma unroll
    for (int mf = 0; mf < 4; ++mf) {
#pragma unroll
      for (int nf = 0; nf < 4; ++nf) {
#pragma unroll
        for (int r = 0; r < 4; ++r) {
          const int row = mf * 16 + r0e + r;
          float gv = acc[mf][nf][r] + biasS[1][row];
          SIG[wn][row][nf * 16 + c0] = (f16)__builtin_amdgcn_rcpf(1.0f + __expf(-gv));
        }
      }
    }
  }
  __syncthreads();
  if (!isG) {
#pragma unroll
    for (int mf = 0; mf < 4; ++mf) {
#pragma unroll
      for (int nf = 0; nf < 4; ++nf) {
#pragma unroll
        for (int r = 0; r < 4; ++r) {
          const int row = mf * 16 + r0e + r;
          const int colc = nf * 16 + c0;
          float av = acc[mf][nf][r] + biasS[0][row];
          float sg = (float)SIG[wn][row][colc];
          out[((size_t)b * Hn + m0 + row) * Ln + l0 + wn * 64 + colc] = av * sg;
        }
      }
    }
  }
#undef STAGE
}

extern "C" void kernel_launch(void* const* d_in, const int* in_sizes, int n_in,
                              void* d_out, int out_size, void* d_ws, size_t ws_size,
                              hipStream_t stream) {
  (void)in_sizes; (void)n_in; (void)out_size; (void)ws_size;
  const float* u     = (const float*)d_in[0];
  const float* C     = (const float*)d_in[1];
  const float* logdt = (const float*)d_in[2];
  const float* logA  = (const float*)d_in[3];
  const float* Aim   = (const float*)d_in[4];
  const float* Dv    = (const float*)d_in[5];
  const float* W     = (const float*)d_in[6];
  const float* bias  = (const float*)d_in[7];
  float* out = (float*)d_out;

  char* ws = (char*)d_ws;
  f16*    gyT  = (f16*)ws;                                  // 32 MB
  f16*    Vg   = (f16*)(ws + (size_t)(32 << 20));           // 4 MB
  f16*    A3g  = (f16*)(ws + (size_t)(36 << 20));           // 8 MB
  float2* w64g = (float2*)(ws + (size_t)(44 << 20));        // 128 KB
  f16*    Wh   = (f16*)(ws + (size_t)(45 << 20));           // 1 MB row-major
  f16*    yg   = (f16*)d_out;                               // dead before K6 writes

  hipLaunchKernelGGL(k_mats1, dim3(Hn), dim3(64), 0, stream, C, logdt, logA, Aim, Vg, A3g, w64g);
  hipLaunchKernelGGL(conv_w, dim3(2048), dim3(256), 0, stream, W, Wh);
  hipLaunchKernelGGL(s4d_mid, dim3(Hn * Bn), dim3(256), 0, stream, u, Vg, A3g, w64g, Dv, yg);
  hipLaunchKernelGGL(k_transpose, dim3(Bn * 8 * 64), dim3(256), 0, stream, yg, gyT);
  hipLaunchKernelGGL(s4d_gemm, dim3(8 * 256), dim3(256), 0, stream, Wh, gyT, bias, out);
}

// Round 15
// 98.036 us; speedup vs baseline: 1.1514x; 1.1514x over previous
//
#include <hip/hip_runtime.h>
#include <hip/hip_bf16.h>

constexpr int Bn = 8, Hn = 512, Ln = 4096, N2n = 32;

typedef _Float16 f16;
typedef __attribute__((ext_vector_type(8))) _Float16 f16x8;
typedef __attribute__((ext_vector_type(4))) _Float16 f16x4;
typedef __attribute__((ext_vector_type(2))) _Float16 f16x2;
typedef __attribute__((ext_vector_type(4))) float f32x4;

typedef void __attribute__((address_space(1))) gvoid;
typedef void __attribute__((address_space(3))) lvoid;

// ============ K0: per-h param matrices (V, full A3 incl Toeplitz, w64) ============
__global__ __launch_bounds__(64) void k_mats1(
    const float* __restrict__ C, const float* __restrict__ log_dt,
    const float* __restrict__ logA, const float* __restrict__ Aim,
    f16* __restrict__ Vg, f16* __restrict__ A3g, float2* __restrict__ w64g) {
  __shared__ f16 VT[64 * 64];
  __shared__ f16 QT[64 * 64];
  __shared__ float kp[64][33];
  __shared__ float ks[64];
  const int h = blockIdx.x, tid = threadIdx.x, n = tid & 31;

  if (tid < 32) {
    const int idx = h * N2n + n;
    float dt = expf(log_dt[h]);
    float Ar = -expf(logA[idx]);
    float Ai = Aim[idx];
    float dr = Ar * dt, di = Ai * dt;
    float er = expf(dr);
    float wr = er * cosf(di), wi = er * sinf(di);
    float den = Ar * Ar + Ai * Ai;
    float e1r = wr - 1.0f, e1i = wi;
    float tr = (e1r * Ar + e1i * Ai) / den;
    float ti = (e1i * Ar - e1r * Ai) / den;
    float Cr = C[idx * 2 + 0], Ci = C[idx * 2 + 1];
    float c2r = 2.0f * (Cr * tr - Ci * ti);
    float c2i = 2.0f * (Cr * ti + Ci * tr);

    float wpr = 1.f, wpi = 0.f;   // w^p
    for (int p = 0; p <= 64; ++p) {
      float cwr = c2r * wpr - c2i * wpi;   // C2 * w^p
      float cwi = c2r * wpi + c2i * wpr;
      if (p < 64) {
        const int j = 63 - p, ch = j >> 3, jo = j & 7;
        const int s0 = 2 * n, s1 = 2 * n + 1;
        VT[s0 * 64 + ((ch ^ (s0 & 7)) * 8) + jo] = (f16)wpr;
        VT[s1 * 64 + ((ch ^ (s1 & 7)) * 8) + jo] = (f16)wpi;
        kp[p][n] = cwr;
      }
      if (p >= 1) {
        const int t = p - 1, c0 = 2 * n;
        const int ch = (c0 >> 3) ^ (t & 7);
        QT[t * 64 + ch * 8 + (c0 & 7)]     = (f16)cwr;
        QT[t * 64 + ch * 8 + (c0 & 7) + 1] = (f16)(-cwi);
      }
      if (p == 64) w64g[h * 32 + n] = make_float2(wpr, wpi);
      float nr = wpr * wr - wpi * wi;
      float ni = wpr * wi + wpi * wr;
      wpr = nr; wpi = ni;
    }
  }
  __syncthreads();
  float s = 0.f;
#pragma unroll
  for (int m = 0; m < 32; ++m) s += kp[tid][m];
  ks[tid] = s;
  __syncthreads();
  const int t = tid;
#pragma unroll
  for (int c = 0; c < 8; ++c) {
    f16x8 row;
#pragma unroll
    for (int jo = 0; jo < 8; ++jo) {
      int j = c * 8 + jo;
      row[jo] = (j <= t) ? (f16)ks[t - j] : (f16)0.f;
    }
    *(f16x8*)&A3g[(size_t)h * 8192 + t * 128 + ((c ^ (t & 7)) * 8)] = row;
  }
#pragma unroll
  for (int c = 0; c < 8; ++c)
    *(f16x8*)&Vg[(size_t)h * 4096 + tid * 64 + c * 8] = *(f16x8*)&VT[tid * 64 + c * 8];
#pragma unroll
  for (int c = 0; c < 8; ++c)
    *(f16x8*)&A3g[(size_t)h * 8192 + tid * 128 + 64 + c * 8] = *(f16x8*)&QT[tid * 64 + c * 8];
}

// ============ K1: W fp32 -> f16 (row-major) ============
__global__ void conv_w(const float* __restrict__ W, f16* __restrict__ Wh) {
  int i = blockIdx.x * 256 + threadIdx.x;
  if (i < 2 * Hn * Hn) Wh[i] = (f16)W[i];
}

// ============ K2: fused middle, one block per (h,b): exactly 32 KB LDS ============
// Pbuf overlays dead-V region of MATS; A3 issue deferred past Pbuf consumption.
// 32 KB -> 5 blocks/CU (was 4).
__global__ __launch_bounds__(256, 5) void s4d_mid(
    const float* __restrict__ u, const f16* __restrict__ Vg,
    const f16* __restrict__ A3g, const float2* __restrict__ w64g,
    const float* __restrict__ Dv, f16* __restrict__ yg) {
  __shared__ f16 MATS[8192];   // 16 KB: V in [0:4096), Pbuf overlay, then A3
  __shared__ f16 U[4096];      // 8 KB: [col=blk][j] chunk^(col&7)
  __shared__ f16 LE[4096];     // 8 KB: [col=blk][st] chunk^(col&7)
  const int tid = threadIdx.x, wid = tid >> 6, lane = tid & 63;
  const int h = ((blockIdx.x >> 6) << 3) | (blockIdx.x & 7);
  const int b = (blockIdx.x >> 3) & 7;
  const float Dh = Dv[h];

#pragma unroll
  for (int q = 0; q < 2; ++q)
    __builtin_amdgcn_global_load_lds((const gvoid*)(Vg + (size_t)h * 4096 + (q * 256 + tid) * 8),
                                     (lvoid*)&MATS[(q * 256 + wid * 64) * 8], 16, 0, 0);
#pragma unroll
  for (int i = 0; i < 4; ++i) {
    int e = (i * 256 + tid) * 4;          // 0..4095
    float4 uv = *(const float4*)(u + ((size_t)(b * Hn + h)) * Ln + e);
    int col = e >> 6, j = e & 63;
    f16x4 hv = {(f16)uv.x, (f16)uv.y, (f16)uv.z, (f16)uv.w};
    *(f16x4*)&U[col * 64 + ((j >> 3) ^ (col & 7)) * 8 + (j & 7)] = hv;
  }
  asm volatile("s_waitcnt vmcnt(0)" ::: "memory");
  __syncthreads();

  // ---- MFMA1: L = V · u  (M=64 st, N=64 cols, K=64) ----
  const int col = wid * 16 + (lane & 15);
  f32x4 acc[4];
#pragma unroll
  for (int i = 0; i < 4; ++i) acc[i] = (f32x4){0.f, 0.f, 0.f, 0.f};
#pragma unroll
  for (int ks = 0; ks < 2; ++ks) {
    const int kc = ks * 4 + (lane >> 4);
    f16x8 bv = *(const f16x8*)&U[col * 64 + ((kc ^ (col & 7)) * 8)];
#pragma unroll
    for (int mf = 0; mf < 4; ++mf) {
      int row = mf * 16 + (lane & 15);
      f16x8 a = *(const f16x8*)&MATS[row * 64 + ((kc ^ (row & 7)) * 8)];
      acc[mf] = __builtin_amdgcn_mfma_f32_16x16x32_f16(a, bv, acc[mf], 0, 0, 0);
    }
  }
  __syncthreads();   // V reads drained; MATS region now dead (A3 NOT yet issued)

  // write L frags to LE: [col][st] chunk^(col&7)
#pragma unroll
  for (int mf = 0; mf < 4; ++mf) {
    int st0 = mf * 16 + (lane >> 4) * 4;
    f16x4 o = {(f16)acc[mf][0], (f16)acc[mf][1], (f16)acc[mf][2], (f16)acc[mf][3]};
    *(f16x4*)&LE[col * 64 + (((st0 >> 3) ^ (col & 7)) << 3) + (st0 & 7)] = o;
  }
  __syncthreads();

  // ---- parallel in-LDS scan; Pbuf overlaid on MATS[0..1KB) ----
  float2* PbufF = (float2*)&MATS[0];      // [q*32+n], 1 KB, dead-V region
  const int n = lane & 31, q = wid;
  const float2 wT = w64g[h * 32 + n];
  float qr = wT.x, qi = wT.y;             // -> w64^16 via 4 squarings
#pragma unroll
  for (int s = 0; s < 4; ++s) {
    float nr = qr * qr - qi * qi;
    float ni = 2.f * qr * qi;
    qr = nr; qi = ni;
  }
  f16x2 Lb[16];
  if (lane < 32) {                        // phase1: local scan, publish quarter-end
    float er = 0.f, ei = 0.f;
#pragma unroll
    for (int k = 0; k < 16; ++k) {
      int blk = q * 16 + k;
      int fi = blk * 64 + (((n >> 2) ^ (blk & 7)) << 3) + ((n & 3) << 1);
      Lb[k] = *(const f16x2*)&LE[fi];
    }
#pragma unroll
    for (int k = 0; k < 16; ++k) {
      float nr = fmaf(wT.x, er, fmaf(-wT.y, ei, (float)Lb[k][0]));
      float ni = fmaf(wT.y, er, fmaf(wT.x, ei, (float)Lb[k][1]));
      er = nr; ei = ni;
    }
    PbufF[q * 32 + n] = make_float2(er, ei);
  }
  __syncthreads();
  float orr = 0.f, oii = 0.f;
  if (lane < 32) {                        // phase2a: combine prefix quarters
    for (int p = 0; p < q; ++p) {
      float2 Pp = PbufF[p * 32 + n];
      float nr = fmaf(qr, orr, fmaf(-qi, oii, Pp.x));
      float ni = fmaf(qi, orr, fmaf(qr, oii, Pp.y));
      orr = nr; oii = ni;
    }
  }
  __syncthreads();                        // all Pbuf reads done; MATS fully free

  // A3 issue now (lands under phase2b + covered by 5-block TLP)
#pragma unroll
  for (int qq = 0; qq < 4; ++qq)
    __builtin_amdgcn_global_load_lds((const gvoid*)(A3g + (size_t)h * 8192 + (qq * 256 + tid) * 8),
                                     (lvoid*)&MATS[(qq * 256 + wid * 64) * 8], 16, 0, 0);

  if (lane < 32) {                        // phase2b: rescan, write E in place
    float er = orr, ei = oii;
#pragma unroll
    for (int k = 0; k < 16; ++k) {
      int blk = q * 16 + k;
      int fi = blk * 64 + (((n >> 2) ^ (blk & 7)) << 3) + ((n & 3) << 1);
      *(f16x2*)&LE[fi] = (f16x2){(f16)er, (f16)ei};
      float nr = fmaf(wT.x, er, fmaf(-wT.y, ei, (float)Lb[k][0]));
      float ni = fmaf(wT.y, er, fmaf(wT.x, ei, (float)Lb[k][1]));
      er = nr; ei = ni;
    }
  }
  asm volatile("s_waitcnt vmcnt(0)" ::: "memory");   // own A3 loads done
  __syncthreads();                                    // everyone's A3 + E visible

  // ---- y-GEMM: A = A3 (MATS 64x128), B = [U | LE] read in place ----
  f32x4 acc4[4];
#pragma unroll
  for (int i = 0; i < 4; ++i) acc4[i] = (f32x4){0.f, 0.f, 0.f, 0.f};
#pragma unroll
  for (int ks = 0; ks < 4; ++ks) {
    const int kc = ks * 4 + (lane >> 4);
    f16x8 bf;
    if (ks < 2) bf = *(const f16x8*)&U[col * 64 + ((kc ^ (col & 7)) << 3)];
    else        bf = *(const f16x8*)&LE[col * 64 + (((kc - 8) ^ (col & 7)) << 3)];
#pragma unroll
    for (int mf = 0; mf < 4; ++mf) {
      int row = mf * 16 + (lane & 15);
      f16x8 af = *(const f16x8*)&MATS[row * 128 + ((kc ^ (row & 7)) << 3)];
      acc4[mf] = __builtin_amdgcn_mfma_f32_16x16x32_f16(af, bf, acc4[mf], 0, 0, 0);
    }
  }
  const int t0 = (lane >> 4) * 4;
#pragma unroll
  for (int mf = 0; mf < 4; ++mf) {
    const int tb = mf * 16 + t0;
    f16x4 uq = *(const f16x4*)&U[col * 64 + (((tb >> 3) ^ (col & 7)) << 3) + (tb & 7)];
    f16x4 o;
#pragma unroll
    for (int r = 0; r < 4; ++r) {
      float v = acc4[mf][r] + Dh * (float)uq[r];
      float g2 = v * fmaf(0.0713548163f, v * v, 1.5957691216f);
      o[r] = (f16)(v * __builtin_amdgcn_rcpf(1.0f + __expf(-g2)));
    }
    *(f16x4*)&yg[((size_t)(b * Hn + h)) * Ln + col * 64 + tb] = o;
  }
}

// ============ K5: transpose y[b][h][l] -> gyT[b][l][h] ============
__global__ __launch_bounds__(256) void k_transpose(
    const f16* __restrict__ yg, f16* __restrict__ gyT) {
  __shared__ float T[64][65];
  const int bid = blockIdx.x, tid = threadIdx.x;
  const int b = bid >> 9, hg = (bid >> 6) & 7, lg = bid & 63;
  const int h0 = hg * 64, l0 = lg * 64;
  const int hi = tid >> 2, lc = (tid & 3) * 16;
  const f16* src = yg + ((size_t)(b * Hn + h0 + hi)) * Ln + l0 + lc;
  f16x8 v0 = *(const f16x8*)src;
  f16x8 v1 = *(const f16x8*)(src + 8);
#pragma unroll
  for (int e = 0; e < 8; ++e) T[lc + e][hi] = (float)v0[e];
#pragma unroll
  for (int e = 0; e < 8; ++e) T[lc + 8 + e][hi] = (float)v1[e];
  __syncthreads();
  const int li = tid >> 2, hc = (tid & 3) * 16;
  f16x8 o0, o1;
#pragma unroll
  for (int e = 0; e < 8; ++e) o0[e] = (f16)T[li][hc + e];
#pragma unroll
  for (int e = 0; e < 8; ++e) o1[e] = (f16)T[li][hc + 8 + e];
  f16* dst = gyT + ((size_t)b * Ln + l0 + li) * Hn + h0 + hc;
  *(f16x8*)dst = o0;
  *(f16x8*)(dst + 8) = o1;
}

// ============ K6: dual GEMM (a,g) + bias + GLU — proven version (41.4 us) ============
// 128x128 tile (dual a+g), BK=64, 4 waves, 48 KB LDS (2 blocks/CU), serial stage,
// T2 swizzle via inverse-swizzled global source. 0 bank conflicts, Mfma 31%.
__global__ __launch_bounds__(256, 2) void s4d_gemm(
    const f16* __restrict__ Wh, const f16* __restrict__ gyT,
    const float* __restrict__ bias, float* __restrict__ out) {
  __shared__ f16 As[2][128][64];
  __shared__ f16 Bs[128][64];
  const int tid = threadIdx.x;
  const int wid = tid >> 6, lane = tid & 63;
  const int ntg = blockIdx.x & 255;
  const int mt = blockIdx.x >> 8;
  const int b = ntg >> 5;
  const int l0 = (ntg & 31) * 128;
  const int m0 = mt * 128;
  const int wm = wid >> 1, wn = wid & 1;

  f32x4 acc[2][4][4];
#pragma unroll
  for (int a = 0; a < 2; ++a)
#pragma unroll
    for (int i = 0; i < 4; ++i)
#pragma unroll
      for (int j = 0; j < 4; ++j) acc[a][i][j] = (f32x4){0.f, 0.f, 0.f, 0.f};

  const int srow = lane >> 3;              // row within 8-row group
  const int sks = ((lane & 7) ^ srow) * 8; // inverse-swizzled source k-offset

  for (int kt = 0; kt < 8; ++kt) {
    const int k0 = kt * 64;
#pragma unroll
    for (int q = 0; q < 4; ++q) {
      const int r8 = wid * 32 + q * 8;
      const f16* srcA = Wh + ((size_t)(m0 + r8 + srow) * 512 + k0 + sks);
      __builtin_amdgcn_global_load_lds((const gvoid*)srcA, (lvoid*)&As[0][r8][0], 16, 0, 0);
      const f16* srcG = Wh + ((size_t)(Hn + m0 + r8 + srow) * 512 + k0 + sks);
      __builtin_amdgcn_global_load_lds((const gvoid*)srcG, (lvoid*)&As[1][r8][0], 16, 0, 0);
      const f16* srcB = gyT + (((size_t)b * Ln + l0 + r8 + srow) * Hn + k0 + sks);
      __builtin_amdgcn_global_load_lds((const gvoid*)srcB, (lvoid*)&Bs[r8][0], 16, 0, 0);
    }
    asm volatile("s_waitcnt vmcnt(0)" ::: "memory");
    __syncthreads();
#pragma unroll
    for (int kk = 0; kk < 2; ++kk) {
      const int kc = kk * 4 + (lane >> 4);   // logical k-chunk
      f16x8 af0[4], af1[4], bfv[4];
#pragma unroll
      for (int mf = 0; mf < 4; ++mf) {
        const int row = wm * 64 + mf * 16 + (lane & 15);
        af0[mf] = *(const f16x8*)&As[0][row][(kc ^ (row & 7)) * 8];
        af1[mf] = *(const f16x8*)&As[1][row][(kc ^ (row & 7)) * 8];
      }
#pragma unroll
      for (int nf = 0; nf < 4; ++nf) {
        const int col = wn * 64 + nf * 16 + (lane & 15);
        bfv[nf] = *(const f16x8*)&Bs[col][(kc ^ (col & 7)) * 8];
      }
#pragma unroll
      for (int mf = 0; mf < 4; ++mf)
#pragma unroll
        for (int nf = 0; nf < 4; ++nf) {
          acc[0][mf][nf] = __builtin_amdgcn_mfma_f32_16x16x32_f16(af0[mf], bfv[nf], acc[0][mf][nf], 0, 0, 0);
          acc[1][mf][nf] = __builtin_amdgcn_mfma_f32_16x16x32_f16(af1[mf], bfv[nf], acc[1][mf][nf], 0, 0, 0);
        }
    }
    __syncthreads();
  }

  const int col = lane & 15, r0 = (lane >> 4) * 4;
#pragma unroll
  for (int mf = 0; mf < 4; ++mf) {
    const int hbase = m0 + wm * 64 + mf * 16 + r0;
#pragma unroll
    for (int nf = 0; nf < 4; ++nf) {
      const int l = l0 + wn * 64 + nf * 16 + col;
      f32x4 va = acc[0][mf][nf], vg = acc[1][mf][nf];
#pragma unroll
      for (int r = 0; r < 4; ++r) {
        const int hh = hbase + r;
        float av = va[r] + bias[hh];
        float gv = vg[r] + bias[Hn + hh];
        float sg = __builtin_amdgcn_rcpf(1.0f + __expf(-gv));
        out[((size_t)b * Hn + hh) * Ln + l] = av * sg;
      }
    }
  }
}

extern "C" void kernel_launch(void* const* d_in, const int* in_sizes, int n_in,
                              void* d_out, int out_size, void* d_ws, size_t ws_size,
                              hipStream_t stream) {
  (void)in_sizes; (void)n_in; (void)out_size; (void)ws_size;
  const float* u     = (const float*)d_in[0];
  const float* C     = (const float*)d_in[1];
  const float* logdt = (const float*)d_in[2];
  const float* logA  = (const float*)d_in[3];
  const float* Aim   = (const float*)d_in[4];
  const float* Dv    = (const float*)d_in[5];
  const float* W     = (const float*)d_in[6];
  const float* bias  = (const float*)d_in[7];
  float* out = (float*)d_out;

  char* ws = (char*)d_ws;
  f16*    gyT  = (f16*)ws;                                  // 32 MB
  f16*    Vg   = (f16*)(ws + (size_t)(32 << 20));           // 4 MB
  f16*    A3g  = (f16*)(ws + (size_t)(36 << 20));           // 8 MB
  float2* w64g = (float2*)(ws + (size_t)(44 << 20));        // 128 KB
  f16*    Wh   = (f16*)(ws + (size_t)(45 << 20));           // 1 MB row-major
  f16*    yg   = (f16*)d_out;                               // dead before K6 writes

  hipLaunchKernelGGL(k_mats1, dim3(Hn), dim3(64), 0, stream, C, logdt, logA, Aim, Vg, A3g, w64g);
  hipLaunchKernelGGL(conv_w, dim3(2048), dim3(256), 0, stream, W, Wh);
  hipLaunchKernelGGL(s4d_mid, dim3(Hn * Bn), dim3(256), 0, stream, u, Vg, A3g, w64g, Dv, yg);
  hipLaunchKernelGGL(k_transpose, dim3(Bn * 8 * 64), dim3(256), 0, stream, yg, gyT);
  hipLaunchKernelGGL(s4d_gemm, dim3(4 * 256), dim3(256), 0, stream, Wh, gyT, bias, out);
}